// Round 28
// baseline (81.500 us; speedup 1.0000x reference)
//
#include <hip/hip_runtime.h>

// Problem sizes
#define NB  131072
#define ND1 40
#define ND2 10
#define NT0 120
#define NT1 5
#define NO0 3

#define NBW 32                  // batches per workgroup
#define XTILE (NBW * ND1 * ND2) // 12800 floats
#define PK  40                  // Ybf row pitch (bf16 elems)

typedef __attribute__((ext_vector_type(8))) short  short8;
typedef __attribute__((ext_vector_type(4))) float  f32x4;

// R22 (44.1 us, 76% of stream ceiling) + nontemporal x-loads: x is read-once,
// 'nt' marks the stream no-allocate in L2 (210 MB would otherwise fully
// thrash the 4 MiB/XCD L2 tag/evict path). Loads go through clang ext_vector
// f32x4 (builtin rejects HIP_vector_type). Only change vs R26.
//  phase 1: load-all (12.5 float4/thread in flight, coalesced 80B units) ->
//           fp32 FMA -> v_cvt_pk_bf16_f32 -> Ybf[u][b][d] in LDS.
//  phase 2: MFMA bf16: Z[t,b]=sum_d W11[t,d]*Y_u[d,b];
//           st += fc4[u]*relu(Z+bias1).
//  epilogue: out[o,b] = sum_t W12[o,t]*st[t,b].
__global__ __launch_bounds__(256, 2) void BL_36721970381090_kernel(
    const float* __restrict__ x,
    const float* __restrict__ W11,
    const float* __restrict__ fc2_w,
    const float* __restrict__ bias1,
    const float* __restrict__ W12,
    const float* __restrict__ fc4_w,
    const float* __restrict__ bias2,
    float* __restrict__ out)
{
    __shared__ __align__(16) unsigned short Ybf[NT1 * NBW * PK]; // 12800 B
    __shared__ float biasL[128 * NT1];                           //  2560 B
    __shared__ float w12L[NO0 * 128];                            //  1536 B
    __shared__ float b2L[4];
    __shared__ float redL[4 * NO0 * NBW];                        //  1536 B

    const int tid = threadIdx.x;
    const int wg  = blockIdx.x;
    const int w   = tid >> 6;   // wave 0..3
    const int l   = tid & 63;
    const int lr  = l & 15;     // A row / B col within 16-tile
    const int lg  = l >> 4;     // k-group

    // ---------------- prologue: constants -> LDS --------------------------
    for (int i = tid; i < 128 * NT1; i += 256)
        biasL[i] = (i < NT0 * NT1) ? bias1[i] : 0.f;
    for (int i = tid; i < NO0 * 128; i += 256) {
        const int o = i >> 7, t = i & 127;
        w12L[i] = (t < NT0) ? W12[o * NT0 + t] : 0.f;
    }
    if (tid < NO0) b2L[tid] = bias2[tid];

    float fc4r[NT1];
#pragma unroll
    for (int u = 0; u < NT1; ++u) fc4r[u] = fc4_w[u];

    // A-fragments: W11 -> bf16, masked (t<120, d<40)
    short8 afr[2][2];
#pragma unroll
    for (int mt = 0; mt < 2; ++mt) {
        const int t  = w * 32 + mt * 16 + lr;
        const int tc = t < NT0 ? t : NT0 - 1;
#pragma unroll
        for (int kk = 0; kk < 2; ++kk) {
            const int cb = kk * 32 + lg * 8;
            const int cc = cb <= 32 ? cb : 0;
            const float4* pw = (const float4*)(W11 + tc * ND1 + cc);
            const float4 w0 = pw[0], w1 = pw[1];
            const bool v = (t < NT0) && (cb <= 32);
            unsigned p01, p23, p45, p67;
            asm("v_cvt_pk_bf16_f32 %0, %1, %2" : "=v"(p01) : "v"(w0.x), "v"(w0.y));
            asm("v_cvt_pk_bf16_f32 %0, %1, %2" : "=v"(p23) : "v"(w0.z), "v"(w0.w));
            asm("v_cvt_pk_bf16_f32 %0, %1, %2" : "=v"(p45) : "v"(w1.x), "v"(w1.y));
            asm("v_cvt_pk_bf16_f32 %0, %1, %2" : "=v"(p67) : "v"(w1.z), "v"(w1.w));
            short8 f;
            f[0] = v ? (short)(p01 & 0xFFFF) : (short)0;
            f[1] = v ? (short)(p01 >> 16)    : (short)0;
            f[2] = v ? (short)(p23 & 0xFFFF) : (short)0;
            f[3] = v ? (short)(p23 >> 16)    : (short)0;
            f[4] = v ? (short)(p45 & 0xFFFF) : (short)0;
            f[5] = v ? (short)(p45 >> 16)    : (short)0;
            f[6] = v ? (short)(p67 & 0xFFFF) : (short)0;
            f[7] = v ? (short)(p67 >> 16)    : (short)0;
            afr[mt][kk] = f;
        }
    }

    // ---------------- phase 1: load-all (nontemporal), then compute -------
    {
        const float* gx = x + (size_t)wg * XTILE;
        unsigned* Yw = (unsigned*)Ybf;
        const bool act2 = (tid < 128);

        f32x4 xq0[5], xq1[5], xq2[5];
        const f32x4* xr0 = (const f32x4*)(gx + (0 * 256 + tid) * 20);
        const f32x4* xr1 = (const f32x4*)(gx + (1 * 256 + tid) * 20);
        const f32x4* xr2 = (const f32x4*)(gx + (2 * 256 + tid) * 20);
#pragma unroll
        for (int i = 0; i < 5; ++i) xq0[i] = __builtin_nontemporal_load(&xr0[i]);
#pragma unroll
        for (int i = 0; i < 5; ++i) xq1[i] = __builtin_nontemporal_load(&xr1[i]);
        if (act2) {
#pragma unroll
            for (int i = 0; i < 5; ++i) xq2[i] = __builtin_nontemporal_load(&xr2[i]);
        }

        const f32x4* bufs[3] = {xq0, xq1, xq2};
#pragma unroll
        for (int rep = 0; rep < 3; ++rep) {
            if (rep < 2 || act2) {
                const int q = rep * 256 + tid;
                const int batch = q / 20;
                const int pair  = q - batch * 20;
                const float* xv = (const float*)bufs[rep];
#pragma unroll
                for (int u = 0; u < NT1; ++u) {
                    float a0 = 0.f, a1 = 0.f;
#pragma unroll
                    for (int s = 0; s < ND2; ++s) {
                        const float fw = fc2_w[u * ND2 + s];   // uniform: s_load
                        a0 = fmaf(xv[s], fw, a0);
                        a1 = fmaf(xv[10 + s], fw, a1);
                    }
                    unsigned pk;
                    asm("v_cvt_pk_bf16_f32 %0, %1, %2" : "=v"(pk) : "v"(a0), "v"(a1));
                    Yw[u * (NBW * PK / 2) + batch * (PK / 2) + pair] = pk;
                }
            }
        }
    }
    __syncthreads();   // Ybf + constants visible

    // ---------------- phase 2: MFMA + fused relu/fc4 ----------------------
    float st[2][2][4];          // [m-tile][n-tile][reg]
#pragma unroll
    for (int mt = 0; mt < 2; ++mt)
#pragma unroll
        for (int nt = 0; nt < 2; ++nt)
#pragma unroll
            for (int r = 0; r < 4; ++r) st[mt][nt][r] = 0.f;

    const short8 zf = {0, 0, 0, 0, 0, 0, 0, 0};
#pragma unroll
    for (int u = 0; u < NT1; ++u) {
        float bv[2][4];
#pragma unroll
        for (int mt = 0; mt < 2; ++mt)
#pragma unroll
            for (int r = 0; r < 4; ++r)
                bv[mt][r] = biasL[(w * 32 + mt * 16 + lg * 4 + r) * NT1 + u];
        const unsigned short* Yu = &Ybf[u * (NBW * PK)];
#pragma unroll
        for (int nt = 0; nt < 2; ++nt) {
            const short8 b0 = *(const short8*)&Yu[(nt * 16 + lr) * PK + lg * 8];
            short8 b1 = zf;
            if (lg == 0) b1 = *(const short8*)&Yu[(nt * 16 + lr) * PK + 32];
#pragma unroll
            for (int mt = 0; mt < 2; ++mt) {
                f32x4 z = {0.f, 0.f, 0.f, 0.f};
                z = __builtin_amdgcn_mfma_f32_16x16x32_bf16(afr[mt][0], b0, z, 0, 0, 0);
                z = __builtin_amdgcn_mfma_f32_16x16x32_bf16(afr[mt][1], b1, z, 0, 0, 0);
#pragma unroll
                for (int r = 0; r < 4; ++r)
                    st[mt][nt][r] += fc4r[u] * fmaxf(z[r] + bv[mt][r], 0.f);
            }
        }
    }

    // ---------------- epilogue: out[o,b] = sum_t W12[o,t]*st --------------
    float po[2][NO0];
#pragma unroll
    for (int nt = 0; nt < 2; ++nt)
#pragma unroll
        for (int o = 0; o < NO0; ++o) {
            float a = 0.f;
#pragma unroll
            for (int mt = 0; mt < 2; ++mt)
#pragma unroll
                for (int r = 0; r < 4; ++r)
                    a = fmaf(w12L[o * 128 + (w * 32 + mt * 16 + lg * 4 + r)],
                             st[mt][nt][r], a);
            a += __shfl_xor(a, 16, 64);
            a += __shfl_xor(a, 32, 64);
            po[nt][o] = a;
        }
    if (l < 16) {
#pragma unroll
        for (int nt = 0; nt < 2; ++nt)
#pragma unroll
            for (int o = 0; o < NO0; ++o)
                redL[(w * NO0 + o) * NBW + nt * 16 + l] = po[nt][o];
    }
    __syncthreads();

    if (tid < NO0 * NBW) {                    // 96 threads
        const int o  = tid >> 5;
        const int bc = tid & 31;
        const float s = redL[(0 * NO0 + o) * NBW + bc]
                      + redL[(1 * NO0 + o) * NBW + bc]
                      + redL[(2 * NO0 + o) * NBW + bc]
                      + redL[(3 * NO0 + o) * NBW + bc]
                      + b2L[o];
        __builtin_nontemporal_store(s, &out[((size_t)wg * NBW + bc) * NO0 + o]);
    }
}

extern "C" void kernel_launch(void* const* d_in, const int* in_sizes, int n_in,
                              void* d_out, int out_size, void* d_ws, size_t ws_size,
                              hipStream_t stream) {
    const float* x      = (const float*)d_in[0];
    const float* W11    = (const float*)d_in[1];
    const float* fc2_w  = (const float*)d_in[2];
    const float* bias1  = (const float*)d_in[3];
    const float* W12    = (const float*)d_in[4];
    const float* fc4_w  = (const float*)d_in[5];
    const float* bias2  = (const float*)d_in[6];
    float* out = (float*)d_out;

    const int blocks = NB / NBW;   // 4096
    BL_36721970381090_kernel<<<blocks, 256, 0, stream>>>(
        x, W11, fc2_w, bias1, W12, fc4_w, bias2, out);
}

// Round 29
// 44.231 us; speedup vs baseline: 1.8426x; 1.8426x over previous
//
#include <hip/hip_runtime.h>

// Problem sizes
#define NB  131072
#define ND1 40
#define ND2 10
#define NT0 120
#define NT1 5
#define NO0 3

#define NBW 32                  // batches per workgroup
#define XTILE (NBW * ND1 * ND2) // 12800 floats
#define PK  40                  // Ybf row pitch (bf16 elems)

typedef __attribute__((ext_vector_type(8))) short  short8;
typedef __attribute__((ext_vector_type(4))) float  f32x4;

// FINAL: R22/R26 (best measured: 44.1-44.3 us = 76% of the 6.29 TB/s
// read-stream ceiling; 210 MB mandatory fp32 x-read -> 33.3 us floor).
//  phase 1: load-all (12.5 float4/thread in flight, coalesced 80B units) ->
//           fp32 FMA -> v_cvt_pk_bf16_f32 -> Ybf[u][b][d] in LDS.
//  phase 2: MFMA bf16: Z[t,b]=sum_d W11[t,d]*Y_u[d,b];
//           st += fc4[u]*relu(Z+bias1).  (t padded to 128, d to 64.)
//  epilogue: out[o,b] = sum_t W12[o,t]*st[t,b].
// All structural neighbors measured worse: depth>2.5 units (spill, R20),
// higher occupancy tiers (reg-cap spill, R9/10/12/24), LDS staging (R15/17),
// counted-vmcnt pipeline (R16), T14 reg prefetch (R21), wave balance (R23),
// 2-wave blocks (R13/24), zero-barrier wave-private (R25), nontemporal (R28).
__global__ __launch_bounds__(256, 2) void BL_36721970381090_kernel(
    const float* __restrict__ x,
    const float* __restrict__ W11,
    const float* __restrict__ fc2_w,
    const float* __restrict__ bias1,
    const float* __restrict__ W12,
    const float* __restrict__ fc4_w,
    const float* __restrict__ bias2,
    float* __restrict__ out)
{
    __shared__ __align__(16) unsigned short Ybf[NT1 * NBW * PK]; // 12800 B
    __shared__ float biasL[128 * NT1];                           //  2560 B
    __shared__ float w12L[NO0 * 128];                            //  1536 B
    __shared__ float b2L[4];
    __shared__ float redL[4 * NO0 * NBW];                        //  1536 B

    const int tid = threadIdx.x;
    const int wg  = blockIdx.x;
    const int w   = tid >> 6;   // wave 0..3
    const int l   = tid & 63;
    const int lr  = l & 15;     // A row / B col within 16-tile
    const int lg  = l >> 4;     // k-group

    // ---------------- prologue: constants -> LDS --------------------------
    for (int i = tid; i < 128 * NT1; i += 256)
        biasL[i] = (i < NT0 * NT1) ? bias1[i] : 0.f;
    for (int i = tid; i < NO0 * 128; i += 256) {
        const int o = i >> 7, t = i & 127;
        w12L[i] = (t < NT0) ? W12[o * NT0 + t] : 0.f;
    }
    if (tid < NO0) b2L[tid] = bias2[tid];

    float fc4r[NT1];
#pragma unroll
    for (int u = 0; u < NT1; ++u) fc4r[u] = fc4_w[u];

    // A-fragments: W11 -> bf16, masked (t<120, d<40)
    short8 afr[2][2];
#pragma unroll
    for (int mt = 0; mt < 2; ++mt) {
        const int t  = w * 32 + mt * 16 + lr;
        const int tc = t < NT0 ? t : NT0 - 1;
#pragma unroll
        for (int kk = 0; kk < 2; ++kk) {
            const int cb = kk * 32 + lg * 8;
            const int cc = cb <= 32 ? cb : 0;
            const float4* pw = (const float4*)(W11 + tc * ND1 + cc);
            const float4 w0 = pw[0], w1 = pw[1];
            const bool v = (t < NT0) && (cb <= 32);
            unsigned p01, p23, p45, p67;
            asm("v_cvt_pk_bf16_f32 %0, %1, %2" : "=v"(p01) : "v"(w0.x), "v"(w0.y));
            asm("v_cvt_pk_bf16_f32 %0, %1, %2" : "=v"(p23) : "v"(w0.z), "v"(w0.w));
            asm("v_cvt_pk_bf16_f32 %0, %1, %2" : "=v"(p45) : "v"(w1.x), "v"(w1.y));
            asm("v_cvt_pk_bf16_f32 %0, %1, %2" : "=v"(p67) : "v"(w1.z), "v"(w1.w));
            short8 f;
            f[0] = v ? (short)(p01 & 0xFFFF) : (short)0;
            f[1] = v ? (short)(p01 >> 16)    : (short)0;
            f[2] = v ? (short)(p23 & 0xFFFF) : (short)0;
            f[3] = v ? (short)(p23 >> 16)    : (short)0;
            f[4] = v ? (short)(p45 & 0xFFFF) : (short)0;
            f[5] = v ? (short)(p45 >> 16)    : (short)0;
            f[6] = v ? (short)(p67 & 0xFFFF) : (short)0;
            f[7] = v ? (short)(p67 >> 16)    : (short)0;
            afr[mt][kk] = f;
        }
    }

    // ---------------- phase 1: load-all, then compute ---------------------
    {
        const float* gx = x + (size_t)wg * XTILE;
        unsigned* Yw = (unsigned*)Ybf;
        const bool act2 = (tid < 128);

        float4 xq0[5], xq1[5], xq2[5];
        const float4* xr0 = (const float4*)(gx + (0 * 256 + tid) * 20);
        const float4* xr1 = (const float4*)(gx + (1 * 256 + tid) * 20);
        const float4* xr2 = (const float4*)(gx + (2 * 256 + tid) * 20);
#pragma unroll
        for (int i = 0; i < 5; ++i) xq0[i] = xr0[i];
#pragma unroll
        for (int i = 0; i < 5; ++i) xq1[i] = xr1[i];
        if (act2) {
#pragma unroll
            for (int i = 0; i < 5; ++i) xq2[i] = xr2[i];
        }

        const float4* bufs[3] = {xq0, xq1, xq2};
#pragma unroll
        for (int rep = 0; rep < 3; ++rep) {
            if (rep < 2 || act2) {
                const int q = rep * 256 + tid;
                const int batch = q / 20;
                const int pair  = q - batch * 20;
                const float* xv = (const float*)bufs[rep];
#pragma unroll
                for (int u = 0; u < NT1; ++u) {
                    float a0 = 0.f, a1 = 0.f;
#pragma unroll
                    for (int s = 0; s < ND2; ++s) {
                        const float fw = fc2_w[u * ND2 + s];   // uniform: s_load
                        a0 = fmaf(xv[s], fw, a0);
                        a1 = fmaf(xv[10 + s], fw, a1);
                    }
                    unsigned pk;
                    asm("v_cvt_pk_bf16_f32 %0, %1, %2" : "=v"(pk) : "v"(a0), "v"(a1));
                    Yw[u * (NBW * PK / 2) + batch * (PK / 2) + pair] = pk;
                }
            }
        }
    }
    __syncthreads();   // Ybf + constants visible

    // ---------------- phase 2: MFMA + fused relu/fc4 ----------------------
    float st[2][2][4];          // [m-tile][n-tile][reg]
#pragma unroll
    for (int mt = 0; mt < 2; ++mt)
#pragma unroll
        for (int nt = 0; nt < 2; ++nt)
#pragma unroll
            for (int r = 0; r < 4; ++r) st[mt][nt][r] = 0.f;

    const short8 zf = {0, 0, 0, 0, 0, 0, 0, 0};
#pragma unroll
    for (int u = 0; u < NT1; ++u) {
        float bv[2][4];
#pragma unroll
        for (int mt = 0; mt < 2; ++mt)
#pragma unroll
            for (int r = 0; r < 4; ++r)
                bv[mt][r] = biasL[(w * 32 + mt * 16 + lg * 4 + r) * NT1 + u];
        const unsigned short* Yu = &Ybf[u * (NBW * PK)];
#pragma unroll
        for (int nt = 0; nt < 2; ++nt) {
            const short8 b0 = *(const short8*)&Yu[(nt * 16 + lr) * PK + lg * 8];
            short8 b1 = zf;
            if (lg == 0) b1 = *(const short8*)&Yu[(nt * 16 + lr) * PK + 32];
#pragma unroll
            for (int mt = 0; mt < 2; ++mt) {
                f32x4 z = {0.f, 0.f, 0.f, 0.f};
                z = __builtin_amdgcn_mfma_f32_16x16x32_bf16(afr[mt][0], b0, z, 0, 0, 0);
                z = __builtin_amdgcn_mfma_f32_16x16x32_bf16(afr[mt][1], b1, z, 0, 0, 0);
#pragma unroll
                for (int r = 0; r < 4; ++r)
                    st[mt][nt][r] += fc4r[u] * fmaxf(z[r] + bv[mt][r], 0.f);
            }
        }
    }

    // ---------------- epilogue: out[o,b] = sum_t W12[o,t]*st --------------
    float po[2][NO0];
#pragma unroll
    for (int nt = 0; nt < 2; ++nt)
#pragma unroll
        for (int o = 0; o < NO0; ++o) {
            float a = 0.f;
#pragma unroll
            for (int mt = 0; mt < 2; ++mt)
#pragma unroll
                for (int r = 0; r < 4; ++r)
                    a = fmaf(w12L[o * 128 + (w * 32 + mt * 16 + lg * 4 + r)],
                             st[mt][nt][r], a);
            a += __shfl_xor(a, 16, 64);
            a += __shfl_xor(a, 32, 64);
            po[nt][o] = a;
        }
    if (l < 16) {
#pragma unroll
        for (int nt = 0; nt < 2; ++nt)
#pragma unroll
            for (int o = 0; o < NO0; ++o)
                redL[(w * NO0 + o) * NBW + nt * 16 + l] = po[nt][o];
    }
    __syncthreads();

    if (tid < NO0 * NBW) {                    // 96 threads
        const int o  = tid >> 5;
        const int bc = tid & 31;
        const float s = redL[(0 * NO0 + o) * NBW + bc]
                      + redL[(1 * NO0 + o) * NBW + bc]
                      + redL[(2 * NO0 + o) * NBW + bc]
                      + redL[(3 * NO0 + o) * NBW + bc]
                      + b2L[o];
        out[((size_t)wg * NBW + bc) * NO0 + o] = s;
    }
}

extern "C" void kernel_launch(void* const* d_in, const int* in_sizes, int n_in,
                              void* d_out, int out_size, void* d_ws, size_t ws_size,
                              hipStream_t stream) {
    const float* x      = (const float*)d_in[0];
    const float* W11    = (const float*)d_in[1];
    const float* fc2_w  = (const float*)d_in[2];
    const float* bias1  = (const float*)d_in[3];
    const float* W12    = (const float*)d_in[4];
    const float* fc4_w  = (const float*)d_in[5];
    const float* bias2  = (const float*)d_in[6];
    float* out = (float*)d_out;

    const int blocks = NB / NBW;   // 4096
    BL_36721970381090_kernel<<<blocks, 256, 0, stream>>>(
        x, W11, fc2_w, bias1, W12, fc4_w, bias2, out);
}